// Round 1
// baseline (330.639 us; speedup 1.0000x reference)
//
#include <hip/hip_runtime.h>
#include <hip/hip_bf16.h>
#include <cstdint>

#define B_  2
#define S_  2048
#define D_  1024
#define H_  16
#define HD_ 64
#define M_  (B_ * S_)   // 4096
static constexpr float SCALE = 0.125f;  // HD^-0.5

typedef __bf16 bf16x8 __attribute__((ext_vector_type(8)));
typedef float  f32x4  __attribute__((ext_vector_type(4)));

__device__ __forceinline__ unsigned short f2b(float f) {
  union { float f; unsigned u; } x; x.f = f;
  unsigned r = x.u + 0x7FFF + ((x.u >> 16) & 1);   // RNE
  return (unsigned short)(r >> 16);
}

// ---------------------------------------------------------------- cvt x -> bf16
__global__ void cvt_x_kernel(const float4* __restrict__ x, ushort4* __restrict__ o, int n4) {
  int i = blockIdx.x * blockDim.x + threadIdx.x;
  if (i >= n4) return;
  float4 v = x[i];
  ushort4 r;
  r.x = f2b(v.x); r.y = f2b(v.y); r.z = f2b(v.z); r.w = f2b(v.w);
  o[i] = r;
}

// ------------------------------------------- transpose + cvt weights: Wt[n][k] = W[k][n]
__global__ void cvt_w_kernel(const float* __restrict__ w0, const float* __restrict__ w1,
                             const float* __restrict__ w2, const float* __restrict__ w3,
                             unsigned short* __restrict__ o0, unsigned short* __restrict__ o1,
                             unsigned short* __restrict__ o2, unsigned short* __restrict__ o3) {
  const float* w = blockIdx.z == 0 ? w0 : blockIdx.z == 1 ? w1 : blockIdx.z == 2 ? w2 : w3;
  unsigned short* o = blockIdx.z == 0 ? o0 : blockIdx.z == 1 ? o1 : blockIdx.z == 2 ? o2 : o3;
  __shared__ float t[32][33];
  int x0 = blockIdx.x * 32, y0 = blockIdx.y * 32;
  int tx = threadIdx.x, ty = threadIdx.y;
#pragma unroll
  for (int j = 0; j < 4; j++)
    t[ty + j * 8][tx] = w[(size_t)(y0 + ty + j * 8) * D_ + x0 + tx];
  __syncthreads();
#pragma unroll
  for (int j = 0; j < 4; j++)
    o[(size_t)(x0 + ty + j * 8) * D_ + y0 + tx] = f2b(t[tx][ty + j * 8]);
}

// ---------------------------------------------------------------- QKV GEMM
// C[m,n] = sum_k xb[m,k] * wt[n,k] + bias[n]; out bf16 [B,H,S,HD]
__global__ __launch_bounds__(256) void qkv_gemm_kernel(
    const unsigned short* __restrict__ xb,
    const unsigned short* __restrict__ wqt, const unsigned short* __restrict__ wkt,
    const unsigned short* __restrict__ wvt,
    const float* __restrict__ bq, const float* __restrict__ bk, const float* __restrict__ bv,
    unsigned short* __restrict__ qo, unsigned short* __restrict__ ko, unsigned short* __restrict__ vo) {
  const unsigned short* wt = blockIdx.z == 0 ? wqt : blockIdx.z == 1 ? wkt : wvt;
  const float* bias        = blockIdx.z == 0 ? bq  : blockIdx.z == 1 ? bk  : bv;
  unsigned short* out      = blockIdx.z == 0 ? qo  : blockIdx.z == 1 ? ko  : vo;

  __shared__ unsigned short As[128 * 40];   // pad 32->40: 2-way bank alias (free)
  __shared__ unsigned short Bs[128 * 40];
  const int tid = threadIdx.x;
  const int lane = tid & 63, wid = tid >> 6;
  const int wm = wid & 1, wn = wid >> 1;
  const int m0 = blockIdx.x * 128, n0 = blockIdx.y * 128;
  const int l15 = lane & 15, q4 = lane >> 4;

  f32x4 zero = {0.f, 0.f, 0.f, 0.f};
  f32x4 acc[4][4];
#pragma unroll
  for (int mt = 0; mt < 4; mt++)
#pragma unroll
    for (int nt = 0; nt < 4; nt++) acc[mt][nt] = zero;

  for (int kb = 0; kb < D_; kb += 32) {
#pragma unroll
    for (int i = 0; i < 2; i++) {
      int ci = tid + i * 256;            // 512 chunks of 8 bf16
      int row = ci >> 2, kc = ci & 3;
      *(uint4*)(As + row * 40 + kc * 8) = *(const uint4*)(xb + (size_t)(m0 + row) * D_ + kb + kc * 8);
      *(uint4*)(Bs + row * 40 + kc * 8) = *(const uint4*)(wt + (size_t)(n0 + row) * D_ + kb + kc * 8);
    }
    __syncthreads();
    bf16x8 af[4], bfv[4];
#pragma unroll
    for (int mt = 0; mt < 4; mt++) af[mt] = *(const bf16x8*)(As + (wm * 64 + mt * 16 + l15) * 40 + q4 * 8);
#pragma unroll
    for (int nt = 0; nt < 4; nt++) bfv[nt] = *(const bf16x8*)(Bs + (wn * 64 + nt * 16 + l15) * 40 + q4 * 8);
#pragma unroll
    for (int mt = 0; mt < 4; mt++)
#pragma unroll
      for (int nt = 0; nt < 4; nt++)
        acc[mt][nt] = __builtin_amdgcn_mfma_f32_16x16x32_bf16(af[mt], bfv[nt], acc[mt][nt], 0, 0, 0);
    __syncthreads();
  }

#pragma unroll
  for (int nt = 0; nt < 4; nt++) {
    int n = n0 + wn * 64 + nt * 16 + l15;
    float bn = bias[n];
    int h = n >> 6, hd = n & 63;
#pragma unroll
    for (int mt = 0; mt < 4; mt++) {
#pragma unroll
      for (int r = 0; r < 4; r++) {
        int m = m0 + wm * 64 + mt * 16 + q4 * 4 + r;   // C row = quad*4 + reg
        int b = m >> 11, s = m & (S_ - 1);
        out[(((size_t)(b * H_ + h)) * S_ + s) * HD_ + hd] = f2b(acc[mt][nt][r] + bn);
      }
    }
  }
}

// ---------------------------------------------------------------- flash attention
// grid (S/64, B*H); block 256 = 4 waves, wave w owns q rows [w*16, w*16+16)
__global__ __launch_bounds__(256) void attn_kernel(
    const unsigned short* __restrict__ Q, const unsigned short* __restrict__ K,
    const unsigned short* __restrict__ V, unsigned short* __restrict__ O) {
  const int qi = blockIdx.x, bh = blockIdx.y;
  const int q0 = qi * 64;
  const unsigned short* Qh = Q + (size_t)bh * S_ * HD_;
  const unsigned short* Kh = K + (size_t)bh * S_ * HD_;
  const unsigned short* Vh = V + (size_t)bh * S_ * HD_;
  const int b = bh >> 4, h = bh & 15;

  __shared__ unsigned short Qs[64 * 72];       // pad 64->72
  __shared__ unsigned short Ks[128 * 72];
  __shared__ unsigned short Vt[64 * 136];      // V transposed: Vt[hd][kk], pad 128->136
  __shared__ unsigned short Ps[4][16 * 136];   // per-wave P (C-layout -> A-layout via LDS)

  const int tid = threadIdx.x, lane = tid & 63, w = tid >> 6;
  const int l15 = lane & 15, q4 = lane >> 4;

#pragma unroll
  for (int i = 0; i < 2; i++) {                // 64 rows x 8 chunks
    int ci = tid + i * 256;
    int row = ci >> 3, kc = ci & 7;
    *(uint4*)(Qs + row * 72 + kc * 8) = *(const uint4*)(Qh + (size_t)(q0 + row) * HD_ + kc * 8);
  }

  float m_i[4], l_i[4];
#pragma unroll
  for (int r = 0; r < 4; r++) { m_i[r] = -1e30f; l_i[r] = 0.f; }
  f32x4 zero = {0.f, 0.f, 0.f, 0.f};
  f32x4 o_acc[4];
#pragma unroll
  for (int nt2 = 0; nt2 < 4; nt2++) o_acc[nt2] = zero;

  const int nkt = (q0 + 63) / 128 + 1;
  for (int kt = 0; kt < nkt; kt++) {
    const int k0 = kt * 128;
    __syncthreads();                           // previous PV done before restage
#pragma unroll
    for (int i = 0; i < 4; i++) {              // K: 128 rows x 8 chunks
      int ci = tid + i * 256;
      int row = ci >> 3, kc = ci & 7;
      *(uint4*)(Ks + row * 72 + kc * 8) = *(const uint4*)(Kh + (size_t)(k0 + row) * HD_ + kc * 8);
    }
#pragma unroll
    for (int i = 0; i < 4; i++) {              // V transposed into Vt
      int ci = tid + i * 256;
      int kk = ci >> 3, hd0 = (ci & 7) * 8;
      union { uint4 u; unsigned short e[8]; } vv;
      vv.u = *(const uint4*)(Vh + (size_t)(k0 + kk) * HD_ + hd0);
#pragma unroll
      for (int j = 0; j < 8; j++) Vt[(hd0 + j) * 136 + kk] = vv.e[j];
    }
    __syncthreads();

    // S = Q K^T  (16 q-rows x 128 keys per wave)
    f32x4 sc[8];
#pragma unroll
    for (int nt = 0; nt < 8; nt++) sc[nt] = zero;
    bf16x8 aq0 = *(const bf16x8*)(Qs + (w * 16 + l15) * 72 + q4 * 8);
    bf16x8 aq1 = *(const bf16x8*)(Qs + (w * 16 + l15) * 72 + 32 + q4 * 8);
#pragma unroll
    for (int nt = 0; nt < 8; nt++) {
      bf16x8 b0 = *(const bf16x8*)(Ks + (nt * 16 + l15) * 72 + q4 * 8);
      bf16x8 b1 = *(const bf16x8*)(Ks + (nt * 16 + l15) * 72 + 32 + q4 * 8);
      sc[nt] = __builtin_amdgcn_mfma_f32_16x16x32_bf16(aq0, b0, sc[nt], 0, 0, 0);
      sc[nt] = __builtin_amdgcn_mfma_f32_16x16x32_bf16(aq1, b1, sc[nt], 0, 0, 0);
    }

    // online softmax (C-layout: row = q4*4+r, col = l15 + nt*16)
    float mnew[4], alpha[4];
#pragma unroll
    for (int r = 0; r < 4; r++) {
      int qrow = q0 + w * 16 + q4 * 4 + r;
      float mx = m_i[r];
#pragma unroll
      for (int nt = 0; nt < 8; nt++) {
        int kcol = k0 + nt * 16 + l15;
        float v = sc[nt][r] * SCALE;
        v = (kcol > qrow) ? -1e30f : v;
        sc[nt][r] = v;
        mx = fmaxf(mx, v);
      }
      for (int off = 1; off < 16; off <<= 1)
        mx = fmaxf(mx, __shfl_xor(mx, off, 64));
      mnew[r] = mx;
      alpha[r] = __expf(m_i[r] - mx);
      m_i[r] = mx;
    }
#pragma unroll
    for (int r = 0; r < 4; r++) {
      float rs = 0.f;
#pragma unroll
      for (int nt = 0; nt < 8; nt++) {
        float p = __expf(sc[nt][r] - mnew[r]);
        sc[nt][r] = p;
        rs += p;
      }
      for (int off = 1; off < 16; off <<= 1)
        rs += __shfl_xor(rs, off, 64);
      l_i[r] = l_i[r] * alpha[r] + rs;
#pragma unroll
      for (int nt2 = 0; nt2 < 4; nt2++) o_acc[nt2][r] *= alpha[r];
    }

    // P: C-layout regs -> LDS row-major (A-layout source)
#pragma unroll
    for (int nt = 0; nt < 8; nt++)
#pragma unroll
      for (int r = 0; r < 4; r++)
        Ps[w][(q4 * 4 + r) * 136 + nt * 16 + l15] = f2b(sc[nt][r]);
    __syncthreads();

    // O += P V
#pragma unroll
    for (int ks = 0; ks < 4; ks++) {
      bf16x8 ap = *(const bf16x8*)(&Ps[w][l15 * 136 + ks * 32 + q4 * 8]);
#pragma unroll
      for (int nt2 = 0; nt2 < 4; nt2++) {
        bf16x8 bv = *(const bf16x8*)(Vt + (nt2 * 16 + l15) * 136 + ks * 32 + q4 * 8);
        o_acc[nt2] = __builtin_amdgcn_mfma_f32_16x16x32_bf16(ap, bv, o_acc[nt2], 0, 0, 0);
      }
    }
  }

  // epilogue: O / l_i -> bf16 [B,S,D]
#pragma unroll
  for (int nt2 = 0; nt2 < 4; nt2++) {
    int hd = nt2 * 16 + l15;
#pragma unroll
    for (int r = 0; r < 4; r++) {
      int s = q0 + w * 16 + q4 * 4 + r;
      float o = o_acc[nt2][r] / l_i[r];
      O[((size_t)(b * S_ + s)) * D_ + h * HD_ + hd] = f2b(o);
    }
  }
}

// ---------------------------------------------------------------- output GEMM (fp32 out)
__global__ __launch_bounds__(256) void out_gemm_kernel(
    const unsigned short* __restrict__ ab, const unsigned short* __restrict__ wot,
    const float* __restrict__ bo, float* __restrict__ out) {
  __shared__ unsigned short As[128 * 40];
  __shared__ unsigned short Bs[128 * 40];
  const int tid = threadIdx.x;
  const int lane = tid & 63, wid = tid >> 6;
  const int wm = wid & 1, wn = wid >> 1;
  const int m0 = blockIdx.x * 128, n0 = blockIdx.y * 128;
  const int l15 = lane & 15, q4 = lane >> 4;

  f32x4 zero = {0.f, 0.f, 0.f, 0.f};
  f32x4 acc[4][4];
#pragma unroll
  for (int mt = 0; mt < 4; mt++)
#pragma unroll
    for (int nt = 0; nt < 4; nt++) acc[mt][nt] = zero;

  for (int kb = 0; kb < D_; kb += 32) {
#pragma unroll
    for (int i = 0; i < 2; i++) {
      int ci = tid + i * 256;
      int row = ci >> 2, kc = ci & 3;
      *(uint4*)(As + row * 40 + kc * 8) = *(const uint4*)(ab  + (size_t)(m0 + row) * D_ + kb + kc * 8);
      *(uint4*)(Bs + row * 40 + kc * 8) = *(const uint4*)(wot + (size_t)(n0 + row) * D_ + kb + kc * 8);
    }
    __syncthreads();
    bf16x8 af[4], bfv[4];
#pragma unroll
    for (int mt = 0; mt < 4; mt++) af[mt] = *(const bf16x8*)(As + (wm * 64 + mt * 16 + l15) * 40 + q4 * 8);
#pragma unroll
    for (int nt = 0; nt < 4; nt++) bfv[nt] = *(const bf16x8*)(Bs + (wn * 64 + nt * 16 + l15) * 40 + q4 * 8);
#pragma unroll
    for (int mt = 0; mt < 4; mt++)
#pragma unroll
      for (int nt = 0; nt < 4; nt++)
        acc[mt][nt] = __builtin_amdgcn_mfma_f32_16x16x32_bf16(af[mt], bfv[nt], acc[mt][nt], 0, 0, 0);
    __syncthreads();
  }

#pragma unroll
  for (int nt = 0; nt < 4; nt++) {
    int n = n0 + wn * 64 + nt * 16 + l15;
    float bn = bo[n];
#pragma unroll
    for (int mt = 0; mt < 4; mt++) {
#pragma unroll
      for (int r = 0; r < 4; r++) {
        int m = m0 + wm * 64 + mt * 16 + q4 * 4 + r;
        out[(size_t)m * D_ + n] = acc[mt][nt][r] + bn;
      }
    }
  }
}

// ---------------------------------------------------------------- launch
extern "C" void kernel_launch(void* const* d_in, const int* in_sizes, int n_in,
                              void* d_out, int out_size, void* d_ws, size_t ws_size,
                              hipStream_t stream) {
  const float* x  = (const float*)d_in[0];
  const float* wq = (const float*)d_in[1];
  const float* bq = (const float*)d_in[2];
  const float* wk = (const float*)d_in[3];
  const float* bk = (const float*)d_in[4];
  const float* wv = (const float*)d_in[5];
  const float* bv = (const float*)d_in[6];
  const float* wo = (const float*)d_in[7];
  const float* bo = (const float*)d_in[8];
  float* out = (float*)d_out;

  char* ws = (char*)d_ws;
  unsigned short* xb  = (unsigned short*)(ws);               // 8 MB; reused for attn out
  unsigned short* wqt = (unsigned short*)(ws + (8u  << 20));
  unsigned short* wkt = (unsigned short*)(ws + (10u << 20));
  unsigned short* wvt = (unsigned short*)(ws + (12u << 20));
  unsigned short* wot = (unsigned short*)(ws + (14u << 20));
  unsigned short* qb  = (unsigned short*)(ws + (16u << 20)); // [B,H,S,HD] bf16
  unsigned short* kb  = (unsigned short*)(ws + (24u << 20));
  unsigned short* vb  = (unsigned short*)(ws + (32u << 20));
  unsigned short* ab  = xb;                                  // attention output [B,S,D] bf16

  cvt_x_kernel<<<dim3(M_ * D_ / 4 / 256), dim3(256), 0, stream>>>((const float4*)x, (ushort4*)xb, M_ * D_ / 4);
  cvt_w_kernel<<<dim3(32, 32, 4), dim3(32, 8), 0, stream>>>(wq, wk, wv, wo, wqt, wkt, wvt, wot);
  qkv_gemm_kernel<<<dim3(32, 8, 3), dim3(256), 0, stream>>>(xb, wqt, wkt, wvt, bq, bk, bv, qb, kb, vb);
  attn_kernel<<<dim3(S_ / 64, B_ * H_), dim3(256), 0, stream>>>(qb, kb, vb, ab);
  out_gemm_kernel<<<dim3(32, 8), dim3(256), 0, stream>>>(ab, wot, bo, out);
}

// Round 2
// 212.749 us; speedup vs baseline: 1.5541x; 1.5541x over previous
//
#include <hip/hip_runtime.h>
#include <hip/hip_bf16.h>
#include <cstdint>

#define B_  2
#define S_  2048
#define D_  1024
#define H_  16
#define HD_ 64
#define M_  (B_ * S_)   // 4096
static constexpr float SC_LOG2E = 0.125f * 1.44269504088896f;  // SCALE * log2(e)

typedef __bf16 bf16x8 __attribute__((ext_vector_type(8)));
typedef float  f32x4  __attribute__((ext_vector_type(4)));

__device__ __forceinline__ unsigned short f2b(float f) {
  union { float f; unsigned u; } x; x.f = f;
  unsigned r = x.u + 0x7FFF + ((x.u >> 16) & 1);   // RNE
  return (unsigned short)(r >> 16);
}

// async global->LDS, 16B per lane; HW uses wave-uniform LDS base + lane*16
__device__ __forceinline__ void gl_lds16(const unsigned short* g, unsigned short* l) {
  __builtin_amdgcn_global_load_lds((const __attribute__((address_space(1))) void*)g,
                                   (__attribute__((address_space(3))) void*)l, 16, 0, 0);
}

// ---------------------------------------------------------------- cvt x -> bf16
__global__ void cvt_x_kernel(const float4* __restrict__ x, ushort4* __restrict__ o, int n4) {
  int i = blockIdx.x * blockDim.x + threadIdx.x;
  if (i >= n4) return;
  float4 v = x[i];
  ushort4 r;
  r.x = f2b(v.x); r.y = f2b(v.y); r.z = f2b(v.z); r.w = f2b(v.w);
  o[i] = r;
}

// ------------------------------------------- transpose + cvt weights: Wt[n][k] = W[k][n]
__global__ void cvt_w_kernel(const float* __restrict__ w0, const float* __restrict__ w1,
                             const float* __restrict__ w2, const float* __restrict__ w3,
                             unsigned short* __restrict__ o0, unsigned short* __restrict__ o1,
                             unsigned short* __restrict__ o2, unsigned short* __restrict__ o3) {
  const float* w = blockIdx.z == 0 ? w0 : blockIdx.z == 1 ? w1 : blockIdx.z == 2 ? w2 : w3;
  unsigned short* o = blockIdx.z == 0 ? o0 : blockIdx.z == 1 ? o1 : blockIdx.z == 2 ? o2 : o3;
  __shared__ float t[32][33];
  int x0 = blockIdx.x * 32, y0 = blockIdx.y * 32;
  int tx = threadIdx.x, ty = threadIdx.y;
#pragma unroll
  for (int j = 0; j < 4; j++)
    t[ty + j * 8][tx] = w[(size_t)(y0 + ty + j * 8) * D_ + x0 + tx];
  __syncthreads();
#pragma unroll
  for (int j = 0; j < 4; j++)
    o[(size_t)(x0 + ty + j * 8) * D_ + y0 + tx] = f2b(t[tx][ty + j * 8]);
}

// ---------------------------------------------------------------- QKV GEMM (m97-style)
// z=0: Q -> [B,H,S,HD]; z=1: K -> [B,H,S,HD]; z=2: V -> [B,H,HD,S] (transposed epilogue)
__global__ __launch_bounds__(256) void qkv_gemm_kernel(
    const unsigned short* __restrict__ xb,
    const unsigned short* __restrict__ wqt, const unsigned short* __restrict__ wkt,
    const unsigned short* __restrict__ wvt,
    const float* __restrict__ bq, const float* __restrict__ bk, const float* __restrict__ bv,
    unsigned short* __restrict__ qo, unsigned short* __restrict__ ko, unsigned short* __restrict__ vo) {
  const unsigned short* wt = blockIdx.z == 0 ? wqt : blockIdx.z == 1 ? wkt : wvt;
  const float* bias        = blockIdx.z == 0 ? bq  : blockIdx.z == 1 ? bk  : bv;
  unsigned short* out      = blockIdx.z == 0 ? qo  : blockIdx.z == 1 ? ko  : vo;

  __shared__ __align__(16) unsigned short As[128 * 32];   // unpadded: global_load_lds layout
  __shared__ __align__(16) unsigned short Bs[128 * 32];
  const int tid = threadIdx.x;
  const int lane = tid & 63, wid = tid >> 6;
  const int wm = wid & 1, wn = wid >> 1;
  const int m0 = blockIdx.x * 128, n0 = blockIdx.y * 128;
  const int l15 = lane & 15, q4 = lane >> 4;

  f32x4 zero = {0.f, 0.f, 0.f, 0.f};
  f32x4 acc[4][4];
#pragma unroll
  for (int mt = 0; mt < 4; mt++)
#pragma unroll
    for (int nt = 0; nt < 4; nt++) acc[mt][nt] = zero;

  for (int kk = 0; kk < D_; kk += 32) {
#pragma unroll
    for (int i = 0; i < 2; i++) {
      int ci = tid + i * 256;            // 512 chunks of 8 bf16 per tile
      int row = ci >> 2, kc = ci & 3;
      gl_lds16(xb + (size_t)(m0 + row) * D_ + kk + kc * 8, As + ci * 8);
      gl_lds16(wt + (size_t)(n0 + row) * D_ + kk + kc * 8, Bs + ci * 8);
    }
    __syncthreads();
    bf16x8 af[4], bfv[4];
#pragma unroll
    for (int mt = 0; mt < 4; mt++) af[mt] = *(const bf16x8*)(As + (wm * 64 + mt * 16 + l15) * 32 + q4 * 8);
#pragma unroll
    for (int nt = 0; nt < 4; nt++) bfv[nt] = *(const bf16x8*)(Bs + (wn * 64 + nt * 16 + l15) * 32 + q4 * 8);
#pragma unroll
    for (int mt = 0; mt < 4; mt++)
#pragma unroll
      for (int nt = 0; nt < 4; nt++)
        acc[mt][nt] = __builtin_amdgcn_mfma_f32_16x16x32_bf16(af[mt], bfv[nt], acc[mt][nt], 0, 0, 0);
    __syncthreads();
  }

  if (blockIdx.z < 2) {
    // Q/K: store [B,H,S,HD]
#pragma unroll
    for (int nt = 0; nt < 4; nt++) {
      int n = n0 + wn * 64 + nt * 16 + l15;
      float bn = bias[n];
      int h = n >> 6, hd = n & 63;
#pragma unroll
      for (int mt = 0; mt < 4; mt++) {
#pragma unroll
        for (int r = 0; r < 4; r++) {
          int m = m0 + wm * 64 + mt * 16 + q4 * 4 + r;   // C row = quad*4 + reg
          int b = m >> 11, s = m & (S_ - 1);
          out[(((size_t)(b * H_ + h)) * S_ + s) * HD_ + hd] = f2b(acc[mt][nt][r] + bn);
        }
      }
    }
  } else {
    // V: transpose via LDS (reuse As, 64x128 bf16 = 8192 elems), store [B,H,HD,S] coalesced
    unsigned short* buf = As;
#pragma unroll
    for (int p = 0; p < 2; p++) {
      __syncthreads();
      if (wn == p) {
#pragma unroll
        for (int nt = 0; nt < 4; nt++) {
          int np = nt * 16 + l15;                    // n' in [0,64)
          float bn = bias[n0 + p * 64 + np];
#pragma unroll
          for (int mt = 0; mt < 4; mt++)
#pragma unroll
            for (int r = 0; r < 4; r++) {
              int ml = wm * 64 + mt * 16 + q4 * 4 + r;
              buf[np * 128 + ml] = f2b(acc[mt][nt][r] + bn);
            }
        }
      }
      __syncthreads();
#pragma unroll
      for (int i = 0; i < 4; i++) {
        int ci = tid + i * 256;                      // 1024 chunks of 8
        int np = ci >> 4, c = ci & 15;
        int n = n0 + p * 64 + np;
        int h = n >> 6, hd = n & 63;
        int m = m0 + c * 8;
        int b = m >> 11, s = m & (S_ - 1);
        *(uint4*)(out + (((size_t)(b * H_ + h)) * HD_ + hd) * S_ + s) = *(const uint4*)(buf + np * 128 + c * 8);
      }
    }
  }
}

// ---------------------------------------------------------------- flash attention (S^T form)
// grid (16, B*H); block = 4 waves. Block x does q-tiles {x, 31-x} (17 k-tiles total, uniform).
// Wave w owns q rows [w*16, w*16+16). S^T = K·Q^T so softmax state is per-lane (q = lane&15)
// and P^T C-regs pack to b64 LDS writes; PV reads P as A-frag, Vt (pre-transposed) as B-frag.
__global__ __launch_bounds__(256) void attn_kernel(
    const unsigned short* __restrict__ Q, const unsigned short* __restrict__ K,
    const unsigned short* __restrict__ Vt_g, unsigned short* __restrict__ O) {
  const int bh = blockIdx.y, b = bh >> 4, h = bh & 15;
  const unsigned short* Qh = Q    + (size_t)bh * S_ * HD_;
  const unsigned short* Kh = K    + (size_t)bh * S_ * HD_;
  const unsigned short* Vh = Vt_g + (size_t)bh * HD_ * S_;   // [HD][S]

  __shared__ __align__(16) unsigned short Qs[64 * 72];
  __shared__ __align__(16) unsigned short Ks[128 * 72];
  __shared__ __align__(16) unsigned short Vt[64 * 136];      // [hd][key]
  __shared__ __align__(16) unsigned short Ps[4][16 * 136];   // per-wave P [q][key]

  const int tid = threadIdx.x, lane = tid & 63, w = tid >> 6;
  const int l15 = lane & 15, q4 = lane >> 4;
  f32x4 zero = {0.f, 0.f, 0.f, 0.f};

  for (int half = 0; half < 2; half++) {
    const int qi = half ? (31 - (int)blockIdx.x) : (int)blockIdx.x;
    const int q0 = qi * 64;
    __syncthreads();                               // prior half's LDS use done
#pragma unroll
    for (int i = 0; i < 2; i++) {
      int ci = tid + i * 256, row = ci >> 3, kc = ci & 7;
      *(uint4*)(Qs + row * 72 + kc * 8) = *(const uint4*)(Qh + (size_t)(q0 + row) * HD_ + kc * 8);
    }

    float m_i = -1e30f, l_i = 0.f;                 // state for q = q0 + w*16 + l15
    f32x4 o_acc[4];
#pragma unroll
    for (int t = 0; t < 4; t++) o_acc[t] = zero;
    const int qrow = q0 + w * 16 + l15;
    const int nkt = qi / 2 + 1;

    for (int kt = 0; kt < nkt; kt++) {
      const int k0 = kt * 128;
      __syncthreads();
#pragma unroll
      for (int i = 0; i < 4; i++) {                // K: 128 rows x 8 chunks
        int ci = tid + i * 256, row = ci >> 3, kc = ci & 7;
        *(uint4*)(Ks + row * 72 + kc * 8) = *(const uint4*)(Kh + (size_t)(k0 + row) * HD_ + kc * 8);
      }
#pragma unroll
      for (int i = 0; i < 4; i++) {                // Vt: 64 rows x 16 chunks (vectorized!)
        int ci = tid + i * 256, hd = ci >> 4, c = ci & 15;
        *(uint4*)(Vt + hd * 136 + c * 8) = *(const uint4*)(Vh + (size_t)hd * S_ + k0 + c * 8);
      }
      __syncthreads();

      // S^T = K·Q^T : A = K-frag (m=key), B = Q-frag (n=q)
      bf16x8 bq0 = *(const bf16x8*)(Qs + (w * 16 + l15) * 72 + q4 * 8);
      bf16x8 bq1 = *(const bf16x8*)(Qs + (w * 16 + l15) * 72 + 32 + q4 * 8);
      f32x4 sc[8];
#pragma unroll
      for (int nt = 0; nt < 8; nt++) sc[nt] = zero;
#pragma unroll
      for (int nt = 0; nt < 8; nt++) {
        bf16x8 ak0 = *(const bf16x8*)(Ks + (nt * 16 + l15) * 72 + q4 * 8);
        bf16x8 ak1 = *(const bf16x8*)(Ks + (nt * 16 + l15) * 72 + 32 + q4 * 8);
        sc[nt] = __builtin_amdgcn_mfma_f32_16x16x32_bf16(ak0, bq0, sc[nt], 0, 0, 0);
        sc[nt] = __builtin_amdgcn_mfma_f32_16x16x32_bf16(ak1, bq1, sc[nt], 0, 0, 0);
      }

      // softmax over keys for q = l15 (C layout: col=l15=q, row=q4*4+r=key)
      const bool needMask = (k0 + 127) > (q0 + w * 16);
      float mx = m_i;
      if (needMask) {
#pragma unroll
        for (int nt = 0; nt < 8; nt++)
#pragma unroll
          for (int r = 0; r < 4; r++) {
            int key = k0 + nt * 16 + q4 * 4 + r;
            float v = sc[nt][r] * SC_LOG2E;
            v = (key > qrow) ? -1e30f : v;
            sc[nt][r] = v;
            mx = fmaxf(mx, v);
          }
      } else {
#pragma unroll
        for (int nt = 0; nt < 8; nt++)
#pragma unroll
          for (int r = 0; r < 4; r++) {
            float v = sc[nt][r] * SC_LOG2E;
            sc[nt][r] = v;
            mx = fmaxf(mx, v);
          }
      }
      mx = fmaxf(mx, __shfl_xor(mx, 16));
      mx = fmaxf(mx, __shfl_xor(mx, 32));
      float alpha = __builtin_amdgcn_exp2f(m_i - mx);
      m_i = mx;
      float rs = 0.f;
#pragma unroll
      for (int nt = 0; nt < 8; nt++)
#pragma unroll
        for (int r = 0; r < 4; r++) {
          float p = __builtin_amdgcn_exp2f(sc[nt][r] - mx);
          sc[nt][r] = p;
          rs += p;
        }
      rs += __shfl_xor(rs, 16);
      rs += __shfl_xor(rs, 32);
      l_i = l_i * alpha + rs;

      // rescale O (O layout: col=l15=hd, row=q4*4+r=q) — broadcast alpha per q
#pragma unroll
      for (int r = 0; r < 4; r++) {
        float ar = __shfl(alpha, q4 * 4 + r);
        o_acc[0][r] *= ar; o_acc[1][r] *= ar; o_acc[2][r] *= ar; o_acc[3][r] *= ar;
      }

      // P^T regs -> Ps[q][key] row-major, packed b64 (4 consecutive keys per reg quad)
#pragma unroll
      for (int nt = 0; nt < 8; nt++) {
        ushort4 pk;
        pk.x = f2b(sc[nt][0]); pk.y = f2b(sc[nt][1]);
        pk.z = f2b(sc[nt][2]); pk.w = f2b(sc[nt][3]);
        *(ushort4*)(&Ps[w][l15 * 136 + nt * 16 + q4 * 4]) = pk;
      }
      __threadfence_block();                        // wave-local LDS write->read ordering

      // O += P V : A = Ps (m=q), B = Vt (n=hd)
#pragma unroll
      for (int ks = 0; ks < 4; ks++) {
        bf16x8 ap = *(const bf16x8*)(&Ps[w][l15 * 136 + ks * 32 + q4 * 8]);
#pragma unroll
        for (int nt2 = 0; nt2 < 4; nt2++) {
          bf16x8 bv = *(const bf16x8*)(Vt + (nt2 * 16 + l15) * 136 + ks * 32 + q4 * 8);
          o_acc[nt2] = __builtin_amdgcn_mfma_f32_16x16x32_bf16(ap, bv, o_acc[nt2], 0, 0, 0);
        }
      }
    }

    // epilogue: O[q=q4*4+r][hd=nt2*16+l15] / l[q] -> bf16 [B,S,D]
#pragma unroll
    for (int r = 0; r < 4; r++) {
      float lr = __shfl(l_i, q4 * 4 + r);
      float inv = 1.0f / lr;
      int s = q0 + w * 16 + q4 * 4 + r;
#pragma unroll
      for (int nt2 = 0; nt2 < 4; nt2++)
        O[((size_t)(b * S_ + s)) * D_ + h * HD_ + nt2 * 16 + l15] = f2b(o_acc[nt2][r] * inv);
    }
  }
}

// ---------------------------------------------------------------- output GEMM (fp32 out, m97-style)
__global__ __launch_bounds__(256) void out_gemm_kernel(
    const unsigned short* __restrict__ ab, const unsigned short* __restrict__ wot,
    const float* __restrict__ bo, float* __restrict__ out) {
  __shared__ __align__(16) unsigned short As[128 * 32];
  __shared__ __align__(16) unsigned short Bs[128 * 32];
  const int tid = threadIdx.x;
  const int lane = tid & 63, wid = tid >> 6;
  const int wm = wid & 1, wn = wid >> 1;
  const int m0 = blockIdx.x * 128, n0 = blockIdx.y * 128;
  const int l15 = lane & 15, q4 = lane >> 4;

  f32x4 zero = {0.f, 0.f, 0.f, 0.f};
  f32x4 acc[4][4];
#pragma unroll
  for (int mt = 0; mt < 4; mt++)
#pragma unroll
    for (int nt = 0; nt < 4; nt++) acc[mt][nt] = zero;

  for (int kk = 0; kk < D_; kk += 32) {
#pragma unroll
    for (int i = 0; i < 2; i++) {
      int ci = tid + i * 256;
      int row = ci >> 2, kc = ci & 3;
      gl_lds16(ab  + (size_t)(m0 + row) * D_ + kk + kc * 8, As + ci * 8);
      gl_lds16(wot + (size_t)(n0 + row) * D_ + kk + kc * 8, Bs + ci * 8);
    }
    __syncthreads();
    bf16x8 af[4], bfv[4];
#pragma unroll
    for (int mt = 0; mt < 4; mt++) af[mt] = *(const bf16x8*)(As + (wm * 64 + mt * 16 + l15) * 32 + q4 * 8);
#pragma unroll
    for (int nt = 0; nt < 4; nt++) bfv[nt] = *(const bf16x8*)(Bs + (wn * 64 + nt * 16 + l15) * 32 + q4 * 8);
#pragma unroll
    for (int mt = 0; mt < 4; mt++)
#pragma unroll
      for (int nt = 0; nt < 4; nt++)
        acc[mt][nt] = __builtin_amdgcn_mfma_f32_16x16x32_bf16(af[mt], bfv[nt], acc[mt][nt], 0, 0, 0);
    __syncthreads();
  }

#pragma unroll
  for (int nt = 0; nt < 4; nt++) {
    int n = n0 + wn * 64 + nt * 16 + l15;
    float bn = bo[n];
#pragma unroll
    for (int mt = 0; mt < 4; mt++) {
#pragma unroll
      for (int r = 0; r < 4; r++) {
        int m = m0 + wm * 64 + mt * 16 + q4 * 4 + r;
        out[(size_t)m * D_ + n] = acc[mt][nt][r] + bn;
      }
    }
  }
}

// ---------------------------------------------------------------- launch
extern "C" void kernel_launch(void* const* d_in, const int* in_sizes, int n_in,
                              void* d_out, int out_size, void* d_ws, size_t ws_size,
                              hipStream_t stream) {
  const float* x  = (const float*)d_in[0];
  const float* wq = (const float*)d_in[1];
  const float* bq = (const float*)d_in[2];
  const float* wk = (const float*)d_in[3];
  const float* bk = (const float*)d_in[4];
  const float* wv = (const float*)d_in[5];
  const float* bv = (const float*)d_in[6];
  const float* wo = (const float*)d_in[7];
  const float* bo = (const float*)d_in[8];
  float* out = (float*)d_out;

  char* ws = (char*)d_ws;
  unsigned short* xb  = (unsigned short*)(ws);               // 8 MB; reused as attn out
  unsigned short* wqt = (unsigned short*)(ws + (8u  << 20));
  unsigned short* wkt = (unsigned short*)(ws + (10u << 20));
  unsigned short* wvt = (unsigned short*)(ws + (12u << 20));
  unsigned short* wot = (unsigned short*)(ws + (14u << 20));
  unsigned short* qb  = (unsigned short*)(ws + (16u << 20)); // [B,H,S,HD] bf16
  unsigned short* kb  = (unsigned short*)(ws + (24u << 20)); // [B,H,S,HD] bf16
  unsigned short* vtg = (unsigned short*)(ws + (32u << 20)); // [B,H,HD,S] bf16 (transposed V)
  unsigned short* ab  = xb;                                  // attention output [B,S,D] bf16

  cvt_x_kernel<<<dim3(M_ * D_ / 4 / 256), dim3(256), 0, stream>>>((const float4*)x, (ushort4*)xb, M_ * D_ / 4);
  cvt_w_kernel<<<dim3(32, 32, 4), dim3(32, 8), 0, stream>>>(wq, wk, wv, wo, wqt, wkt, wvt, wot);
  qkv_gemm_kernel<<<dim3(32, 8, 3), dim3(256), 0, stream>>>(xb, wqt, wkt, wvt, bq, bk, bv, qb, kb, vtg);
  attn_kernel<<<dim3(16, B_ * H_), dim3(256), 0, stream>>>(qb, kb, vtg, ab);
  out_gemm_kernel<<<dim3(32, 8), dim3(256), 0, stream>>>(ab, wot, bo, out);
}

// Round 3
// 205.888 us; speedup vs baseline: 1.6059x; 1.0333x over previous
//
#include <hip/hip_runtime.h>
#include <hip/hip_bf16.h>
#include <cstdint>

#define B_  2
#define S_  2048
#define D_  1024
#define H_  16
#define HD_ 64
#define M_  (B_ * S_)   // 4096
static constexpr float SC_LOG2E = 0.125f * 1.44269504088896f;  // SCALE * log2(e), folded into Q

typedef __bf16 bf16x8 __attribute__((ext_vector_type(8)));
typedef float  f32x4  __attribute__((ext_vector_type(4)));

__device__ __forceinline__ unsigned short f2b(float f) {
  union { float f; unsigned u; } x; x.f = f;
  unsigned r = x.u + 0x7FFF + ((x.u >> 16) & 1);   // RNE
  return (unsigned short)(r >> 16);
}

// async global->LDS, 16B per lane; HW uses wave-uniform LDS base + lane*16
__device__ __forceinline__ void gl_lds16(const unsigned short* g, unsigned short* l) {
  __builtin_amdgcn_global_load_lds((const __attribute__((address_space(1))) void*)g,
                                   (__attribute__((address_space(3))) void*)l, 16, 0, 0);
}

// ------------------------------------------- fused cvt: z<4 -> transpose+cvt W, z==4 -> cvt x
__global__ void cvt_all_kernel(const float* __restrict__ x,
                               const float* __restrict__ w0, const float* __restrict__ w1,
                               const float* __restrict__ w2, const float* __restrict__ w3,
                               unsigned short* __restrict__ xb,
                               unsigned short* __restrict__ o0, unsigned short* __restrict__ o1,
                               unsigned short* __restrict__ o2, unsigned short* __restrict__ o3) {
  int tx = threadIdx.x, ty = threadIdx.y;
  if (blockIdx.z == 4) {
    int tid = ty * 32 + tx;
    int base = ((int)blockIdx.y * 32 + (int)blockIdx.x) * 1024 + tid;  // f4 index
    const float4* xf = (const float4*)x;
    ushort4* ob = (ushort4*)xb;
#pragma unroll
    for (int j = 0; j < 4; j++) {
      float4 v = xf[base + j * 256];
      ushort4 r;
      r.x = f2b(v.x); r.y = f2b(v.y); r.z = f2b(v.z); r.w = f2b(v.w);
      ob[base + j * 256] = r;
    }
    return;
  }
  const float* w = blockIdx.z == 0 ? w0 : blockIdx.z == 1 ? w1 : blockIdx.z == 2 ? w2 : w3;
  unsigned short* o = blockIdx.z == 0 ? o0 : blockIdx.z == 1 ? o1 : blockIdx.z == 2 ? o2 : o3;
  __shared__ float t[32][33];
  int x0 = blockIdx.x * 32, y0 = blockIdx.y * 32;
#pragma unroll
  for (int j = 0; j < 4; j++)
    t[ty + j * 8][tx] = w[(size_t)(y0 + ty + j * 8) * D_ + x0 + tx];
  __syncthreads();
#pragma unroll
  for (int j = 0; j < 4; j++)
    o[(size_t)(x0 + ty + j * 8) * D_ + y0 + tx] = f2b(t[tx][ty + j * 8]);
}

// ---------------------------------------------------------------- QKV GEMM (m97-style)
// z=0: Q*SC_LOG2E -> [B,H,S,HD]; z=1: K -> [B,H,S,HD]; z=2: V -> [B,H,HD,S] (transposed)
__global__ __launch_bounds__(256) void qkv_gemm_kernel(
    const unsigned short* __restrict__ xb,
    const unsigned short* __restrict__ wqt, const unsigned short* __restrict__ wkt,
    const unsigned short* __restrict__ wvt,
    const float* __restrict__ bq, const float* __restrict__ bk, const float* __restrict__ bv,
    unsigned short* __restrict__ qo, unsigned short* __restrict__ ko, unsigned short* __restrict__ vo) {
  const unsigned short* wt = blockIdx.z == 0 ? wqt : blockIdx.z == 1 ? wkt : wvt;
  const float* bias        = blockIdx.z == 0 ? bq  : blockIdx.z == 1 ? bk  : bv;
  unsigned short* out      = blockIdx.z == 0 ? qo  : blockIdx.z == 1 ? ko  : vo;
  const float scl = blockIdx.z == 0 ? SC_LOG2E : 1.0f;

  __shared__ __align__(16) unsigned short As[128 * 32];   // unpadded: global_load_lds layout
  __shared__ __align__(16) unsigned short Bs[128 * 32];
  const int tid = threadIdx.x;
  const int lane = tid & 63, wid = tid >> 6;
  const int wm = wid & 1, wn = wid >> 1;
  const int m0 = blockIdx.x * 128, n0 = blockIdx.y * 128;
  const int l15 = lane & 15, q4 = lane >> 4;

  f32x4 zero = {0.f, 0.f, 0.f, 0.f};
  f32x4 acc[4][4];
#pragma unroll
  for (int mt = 0; mt < 4; mt++)
#pragma unroll
    for (int nt = 0; nt < 4; nt++) acc[mt][nt] = zero;

  for (int kk = 0; kk < D_; kk += 32) {
#pragma unroll
    for (int i = 0; i < 2; i++) {
      int ci = tid + i * 256;            // 512 chunks of 8 bf16 per tile
      int row = ci >> 2, kc = ci & 3;
      gl_lds16(xb + (size_t)(m0 + row) * D_ + kk + kc * 8, As + ci * 8);
      gl_lds16(wt + (size_t)(n0 + row) * D_ + kk + kc * 8, Bs + ci * 8);
    }
    __syncthreads();
    bf16x8 af[4], bfv[4];
#pragma unroll
    for (int mt = 0; mt < 4; mt++) af[mt] = *(const bf16x8*)(As + (wm * 64 + mt * 16 + l15) * 32 + q4 * 8);
#pragma unroll
    for (int nt = 0; nt < 4; nt++) bfv[nt] = *(const bf16x8*)(Bs + (wn * 64 + nt * 16 + l15) * 32 + q4 * 8);
#pragma unroll
    for (int mt = 0; mt < 4; mt++)
#pragma unroll
      for (int nt = 0; nt < 4; nt++)
        acc[mt][nt] = __builtin_amdgcn_mfma_f32_16x16x32_bf16(af[mt], bfv[nt], acc[mt][nt], 0, 0, 0);
    __syncthreads();
  }

  if (blockIdx.z < 2) {
    // Q/K: store [B,H,S,HD]
#pragma unroll
    for (int nt = 0; nt < 4; nt++) {
      int n = n0 + wn * 64 + nt * 16 + l15;
      float bn = bias[n];
      int h = n >> 6, hd = n & 63;
#pragma unroll
      for (int mt = 0; mt < 4; mt++) {
#pragma unroll
        for (int r = 0; r < 4; r++) {
          int m = m0 + wm * 64 + mt * 16 + q4 * 4 + r;   // C row = quad*4 + reg
          int b = m >> 11, s = m & (S_ - 1);
          out[(((size_t)(b * H_ + h)) * S_ + s) * HD_ + hd] = f2b((acc[mt][nt][r] + bn) * scl);
        }
      }
    }
  } else {
    // V: transpose via LDS (reuse As, 64x128 bf16), store [B,H,HD,S] coalesced
    unsigned short* buf = As;
#pragma unroll
    for (int p = 0; p < 2; p++) {
      __syncthreads();
      if (wn == p) {
#pragma unroll
        for (int nt = 0; nt < 4; nt++) {
          int np = nt * 16 + l15;                    // n' in [0,64)
          float bn = bias[n0 + p * 64 + np];
#pragma unroll
          for (int mt = 0; mt < 4; mt++)
#pragma unroll
            for (int r = 0; r < 4; r++) {
              int ml = wm * 64 + mt * 16 + q4 * 4 + r;
              buf[np * 128 + ml] = f2b(acc[mt][nt][r] + bn);
            }
        }
      }
      __syncthreads();
#pragma unroll
      for (int i = 0; i < 4; i++) {
        int ci = tid + i * 256;                      // 1024 chunks of 8
        int np = ci >> 4, c = ci & 15;
        int n = n0 + p * 64 + np;
        int h = n >> 6, hd = n & 63;
        int m = m0 + c * 8;
        int b = m >> 11, s = m & (S_ - 1);
        *(uint4*)(out + (((size_t)(b * H_ + h)) * HD_ + hd) * S_ + s) = *(const uint4*)(buf + np * 128 + c * 8);
      }
    }
  }
}

// ---------------------------------------------------------------- flash attention (S^T form)
// grid (8, B*H); block = 8 waves (512 thr), 128 q-rows. Block x does q-tiles {x, 15-x}
// (17 k-tiles total, uniform). Wave w owns q rows [w*16, w*16+16). K/V staged once per
// 128 q-rows (2x reuse vs r2); tile kt+1 prefetched into regs during compute on kt.
__global__ __launch_bounds__(512) void attn_kernel(
    const unsigned short* __restrict__ Q, const unsigned short* __restrict__ K,
    const unsigned short* __restrict__ Vt_g, unsigned short* __restrict__ O) {
  const int bh = blockIdx.y, b = bh >> 4, h = bh & 15;
  const unsigned short* Qh = Q    + (size_t)bh * S_ * HD_;
  const unsigned short* Kh = K    + (size_t)bh * S_ * HD_;
  const unsigned short* Vh = Vt_g + (size_t)bh * HD_ * S_;   // [HD][S]

  __shared__ __align__(16) unsigned short Qs[128 * 72];
  __shared__ __align__(16) unsigned short Ks[128 * 72];
  __shared__ __align__(16) unsigned short Vt[64 * 136];      // [hd][key]
  __shared__ __align__(16) unsigned short Ps[8][16 * 136];   // per-wave P [q][key]

  const int tid = threadIdx.x, lane = tid & 63, w = tid >> 6;
  const int l15 = lane & 15, q4 = lane >> 4;
  f32x4 zero = {0.f, 0.f, 0.f, 0.f};

  const int krow0 = tid >> 3, kcol0 = (tid & 7) * 8;          // K stage slots (this thread)
  const int vrow0 = tid >> 4, vcol0 = (tid & 15) * 8;         // Vt stage slots

  for (int half = 0; half < 2; half++) {
    const int qi = half ? (15 - (int)blockIdx.x) : (int)blockIdx.x;
    const int q0 = qi * 128;
    __syncthreads();                               // prior half's LDS reads done
#pragma unroll
    for (int i = 0; i < 2; i++) {                  // Qs: 128 rows x 8 chunks
      int ci = tid + i * 512, row = ci >> 3, kc = ci & 7;
      *(uint4*)(Qs + row * 72 + kc * 8) = *(const uint4*)(Qh + (size_t)(q0 + row) * HD_ + kc * 8);
    }

    float m_i = -1e30f, l_i = 0.f;                 // state for q = q0 + w*16 + l15
    f32x4 o_acc[4];
#pragma unroll
    for (int t = 0; t < 4; t++) o_acc[t] = zero;
    const int qrow = q0 + w * 16 + l15;
    const int nkt = qi + 1;

    // prefetch tile 0 into regs
    uint4 kp0 = *(const uint4*)(Kh + (size_t)krow0 * HD_ + kcol0);
    uint4 kp1 = *(const uint4*)(Kh + (size_t)(krow0 + 64) * HD_ + kcol0);
    uint4 vp0 = *(const uint4*)(Vh + (size_t)vrow0 * S_ + vcol0);
    uint4 vp1 = *(const uint4*)(Vh + (size_t)(vrow0 + 32) * S_ + vcol0);

    for (int kt = 0; kt < nkt; kt++) {
      const int k0 = kt * 128;
      __syncthreads();                             // prior tile's LDS reads done
      *(uint4*)(Ks + krow0 * 72 + kcol0) = kp0;
      *(uint4*)(Ks + (krow0 + 64) * 72 + kcol0) = kp1;
      *(uint4*)(Vt + vrow0 * 136 + vcol0) = vp0;
      *(uint4*)(Vt + (vrow0 + 32) * 136 + vcol0) = vp1;
      if (kt + 1 < nkt) {                          // prefetch next tile (overlaps compute)
        int kn = k0 + 128;
        kp0 = *(const uint4*)(Kh + (size_t)(kn + krow0) * HD_ + kcol0);
        kp1 = *(const uint4*)(Kh + (size_t)(kn + krow0 + 64) * HD_ + kcol0);
        vp0 = *(const uint4*)(Vh + (size_t)vrow0 * S_ + kn + vcol0);
        vp1 = *(const uint4*)(Vh + (size_t)(vrow0 + 32) * S_ + kn + vcol0);
      }
      __syncthreads();                             // staging visible

      // S^T = K·Q^T : A = K-frag (m=key), B = Q-frag (n=q); Q pre-scaled by SC_LOG2E
      bf16x8 bq0 = *(const bf16x8*)(Qs + (w * 16 + l15) * 72 + q4 * 8);
      bf16x8 bq1 = *(const bf16x8*)(Qs + (w * 16 + l15) * 72 + 32 + q4 * 8);
      f32x4 sc[8];
#pragma unroll
      for (int nt = 0; nt < 8; nt++) sc[nt] = zero;
#pragma unroll
      for (int nt = 0; nt < 8; nt++) {
        bf16x8 ak0 = *(const bf16x8*)(Ks + (nt * 16 + l15) * 72 + q4 * 8);
        bf16x8 ak1 = *(const bf16x8*)(Ks + (nt * 16 + l15) * 72 + 32 + q4 * 8);
        sc[nt] = __builtin_amdgcn_mfma_f32_16x16x32_bf16(ak0, bq0, sc[nt], 0, 0, 0);
        sc[nt] = __builtin_amdgcn_mfma_f32_16x16x32_bf16(ak1, bq1, sc[nt], 0, 0, 0);
      }

      // softmax over keys for q = l15 (C layout: col=l15=q, row=q4*4+r=key), log2 domain
      const bool needMask = (k0 + 127) > (q0 + w * 16);
      float mx = m_i;
      if (needMask) {
#pragma unroll
        for (int nt = 0; nt < 8; nt++)
#pragma unroll
          for (int r = 0; r < 4; r++) {
            int key = k0 + nt * 16 + q4 * 4 + r;
            float v = (key > qrow) ? -1e30f : sc[nt][r];
            sc[nt][r] = v;
            mx = fmaxf(mx, v);
          }
      } else {
#pragma unroll
        for (int nt = 0; nt < 8; nt++)
#pragma unroll
          for (int r = 0; r < 4; r++) mx = fmaxf(mx, sc[nt][r]);
      }
      mx = fmaxf(mx, __shfl_xor(mx, 16));
      mx = fmaxf(mx, __shfl_xor(mx, 32));
      float alpha = __builtin_amdgcn_exp2f(m_i - mx);
      m_i = mx;
      float rs = 0.f;
#pragma unroll
      for (int nt = 0; nt < 8; nt++)
#pragma unroll
        for (int r = 0; r < 4; r++) {
          float p = __builtin_amdgcn_exp2f(sc[nt][r] - mx);
          sc[nt][r] = p;
          rs += p;
        }
      rs += __shfl_xor(rs, 16);
      rs += __shfl_xor(rs, 32);
      l_i = l_i * alpha + rs;

      // rescale O (O layout: col=l15=hd, row=q4*4+r=q) — broadcast alpha per q
#pragma unroll
      for (int r = 0; r < 4; r++) {
        float ar = __shfl(alpha, q4 * 4 + r);
        o_acc[0][r] *= ar; o_acc[1][r] *= ar; o_acc[2][r] *= ar; o_acc[3][r] *= ar;
      }

      // P^T regs -> Ps[q][key] row-major, packed b64 (4 consecutive keys per reg quad)
#pragma unroll
      for (int nt = 0; nt < 8; nt++) {
        ushort4 pk;
        pk.x = f2b(sc[nt][0]); pk.y = f2b(sc[nt][1]);
        pk.z = f2b(sc[nt][2]); pk.w = f2b(sc[nt][3]);
        *(ushort4*)(&Ps[w][l15 * 136 + nt * 16 + q4 * 4]) = pk;
      }
      __threadfence_block();                        // wave-local LDS write->read ordering

      // O += P V : A = Ps (m=q), B = Vt (n=hd)
#pragma unroll
      for (int ks = 0; ks < 4; ks++) {
        bf16x8 ap = *(const bf16x8*)(&Ps[w][l15 * 136 + ks * 32 + q4 * 8]);
#pragma unroll
        for (int nt2 = 0; nt2 < 4; nt2++) {
          bf16x8 bv = *(const bf16x8*)(Vt + (nt2 * 16 + l15) * 136 + ks * 32 + q4 * 8);
          o_acc[nt2] = __builtin_amdgcn_mfma_f32_16x16x32_bf16(ap, bv, o_acc[nt2], 0, 0, 0);
        }
      }
    }

    // epilogue: O[q=q4*4+r][hd=nt2*16+l15] / l[q] -> bf16 [B,S,D]
#pragma unroll
    for (int r = 0; r < 4; r++) {
      float lr = __shfl(l_i, q4 * 4 + r);
      float inv = 1.0f / lr;
      int s = q0 + w * 16 + q4 * 4 + r;
#pragma unroll
      for (int nt2 = 0; nt2 < 4; nt2++)
        O[((size_t)(b * S_ + s)) * D_ + h * HD_ + nt2 * 16 + l15] = f2b(o_acc[nt2][r] * inv);
    }
  }
}

// ---------------------------------------------------------------- output GEMM (fp32 out, m97-style)
__global__ __launch_bounds__(256) void out_gemm_kernel(
    const unsigned short* __restrict__ ab, const unsigned short* __restrict__ wot,
    const float* __restrict__ bo, float* __restrict__ out) {
  __shared__ __align__(16) unsigned short As[128 * 32];
  __shared__ __align__(16) unsigned short Bs[128 * 32];
  const int tid = threadIdx.x;
  const int lane = tid & 63, wid = tid >> 6;
  const int wm = wid & 1, wn = wid >> 1;
  const int m0 = blockIdx.x * 128, n0 = blockIdx.y * 128;
  const int l15 = lane & 15, q4 = lane >> 4;

  f32x4 zero = {0.f, 0.f, 0.f, 0.f};
  f32x4 acc[4][4];
#pragma unroll
  for (int mt = 0; mt < 4; mt++)
#pragma unroll
    for (int nt = 0; nt < 4; nt++) acc[mt][nt] = zero;

  for (int kk = 0; kk < D_; kk += 32) {
#pragma unroll
    for (int i = 0; i < 2; i++) {
      int ci = tid + i * 256;
      int row = ci >> 2, kc = ci & 3;
      gl_lds16(ab  + (size_t)(m0 + row) * D_ + kk + kc * 8, As + ci * 8);
      gl_lds16(wot + (size_t)(n0 + row) * D_ + kk + kc * 8, Bs + ci * 8);
    }
    __syncthreads();
    bf16x8 af[4], bfv[4];
#pragma unroll
    for (int mt = 0; mt < 4; mt++) af[mt] = *(const bf16x8*)(As + (wm * 64 + mt * 16 + l15) * 32 + q4 * 8);
#pragma unroll
    for (int nt = 0; nt < 4; nt++) bfv[nt] = *(const bf16x8*)(Bs + (wn * 64 + nt * 16 + l15) * 32 + q4 * 8);
#pragma unroll
    for (int mt = 0; mt < 4; mt++)
#pragma unroll
      for (int nt = 0; nt < 4; nt++)
        acc[mt][nt] = __builtin_amdgcn_mfma_f32_16x16x32_bf16(af[mt], bfv[nt], acc[mt][nt], 0, 0, 0);
    __syncthreads();
  }

#pragma unroll
  for (int nt = 0; nt < 4; nt++) {
    int n = n0 + wn * 64 + nt * 16 + l15;
    float bn = bo[n];
#pragma unroll
    for (int mt = 0; mt < 4; mt++) {
#pragma unroll
      for (int r = 0; r < 4; r++) {
        int m = m0 + wm * 64 + mt * 16 + q4 * 4 + r;
        out[(size_t)m * D_ + n] = acc[mt][nt][r] + bn;
      }
    }
  }
}

// ---------------------------------------------------------------- launch
extern "C" void kernel_launch(void* const* d_in, const int* in_sizes, int n_in,
                              void* d_out, int out_size, void* d_ws, size_t ws_size,
                              hipStream_t stream) {
  const float* x  = (const float*)d_in[0];
  const float* wq = (const float*)d_in[1];
  const float* bq = (const float*)d_in[2];
  const float* wk = (const float*)d_in[3];
  const float* bk = (const float*)d_in[4];
  const float* wv = (const float*)d_in[5];
  const float* bv = (const float*)d_in[6];
  const float* wo = (const float*)d_in[7];
  const float* bo = (const float*)d_in[8];
  float* out = (float*)d_out;

  char* ws = (char*)d_ws;
  unsigned short* xb  = (unsigned short*)(ws);               // 8 MB; reused as attn out
  unsigned short* wqt = (unsigned short*)(ws + (8u  << 20));
  unsigned short* wkt = (unsigned short*)(ws + (10u << 20));
  unsigned short* wvt = (unsigned short*)(ws + (12u << 20));
  unsigned short* wot = (unsigned short*)(ws + (14u << 20));
  unsigned short* qb  = (unsigned short*)(ws + (16u << 20)); // [B,H,S,HD] bf16 (pre-scaled)
  unsigned short* kb  = (unsigned short*)(ws + (24u << 20)); // [B,H,S,HD] bf16
  unsigned short* vtg = (unsigned short*)(ws + (32u << 20)); // [B,H,HD,S] bf16 (transposed V)
  unsigned short* ab  = xb;                                  // attention output [B,S,D] bf16

  cvt_all_kernel<<<dim3(32, 32, 5), dim3(32, 8), 0, stream>>>(x, wq, wk, wv, wo, xb, wqt, wkt, wvt, wot);
  qkv_gemm_kernel<<<dim3(32, 8, 3), dim3(256), 0, stream>>>(xb, wqt, wkt, wvt, bq, bk, bv, qb, kb, vtg);
  attn_kernel<<<dim3(8, B_ * H_), dim3(512), 0, stream>>>(qb, kb, vtg, ab);
  out_gemm_kernel<<<dim3(32, 8), dim3(256), 0, stream>>>(ab, wot, bo, out);
}